// Round 10
// baseline (11509.155 us; speedup 1.0000x reference)
//
#include <hip/hip_runtime.h>
#include <hip/hip_fp16.h>

// LSTM: B=32, T=4096, D=256, H=256, gates=1024 (i,g,f,o), HORIZON=24
// r10 = r9 resubmit (r9 bench was an infra failure, not a kernel verdict) + a
// sched_barrier fence after the SMEM issue block so the compiler cannot sink the
// s_loads toward consumption (which would recreate r6's serial-latency failure).
//   - h pairs 0..63: global 256B double-buffer, re-read per step by each wave via
//     s_dcache_inv + 4x s_load_dwordx16 (64 SGPRs); issued first, consumed LAST.
//     fdot2 reads the SGPR operand directly (1 scalar src allowed).
//   - h pairs 64..127: LDS uniform b128 (16/wave), parity double-buffered.
//   - tail weights (pairs 112..127 = 8 quads): streamed from global each step.
//   - gate-local pairing + shfl_xor epilogue + ONE barrier/step (r8 skeleton).

#define T_STEPS 4096
#define BATCH 32
#define RPAIRS 112   // pairs 0..111 resident
#define GQUADS 8     // pairs 112..127 streamed from global

typedef short short8 __attribute__((ext_vector_type(8)));
typedef float f32x4 __attribute__((ext_vector_type(4)));
typedef _Float16 half2_t __attribute__((ext_vector_type(2)));
typedef unsigned int u32x16 __attribute__((ext_vector_type(16)));

__device__ inline unsigned short f32_to_bf16(float f) {
  unsigned int u = __builtin_bit_cast(unsigned int, f);
  u = u + 0x7fffu + ((u >> 16) & 1u);   // RNE
  return (unsigned short)(u >> 16);
}

__device__ inline float fdot2f(unsigned int w, unsigned int h, float acc) {
#if __has_builtin(__builtin_amdgcn_fdot2)
  return __builtin_amdgcn_fdot2(__builtin_bit_cast(half2_t, w),
                                __builtin_bit_cast(half2_t, h), acc, false);
#else
  half2_t a = __builtin_bit_cast(half2_t, w);
  half2_t b = __builtin_bit_cast(half2_t, h);
  acc += (float)a.x * (float)b.x;
  acc += (float)a.y * (float)b.y;
  return acc;
#endif
}

// ---------------- prep: x f32 -> bf16 ----------------
__global__ void k_prep_x(const float4* __restrict__ x, unsigned short* __restrict__ xbf, int n4) {
  int i = blockIdx.x * blockDim.x + threadIdx.x;
  if (i >= n4) return;
  float4 v = x[i];
  ushort4 o;
  o.x = f32_to_bf16(v.x); o.y = f32_to_bf16(v.y);
  o.z = f32_to_bf16(v.z); o.w = f32_to_bf16(v.w);
  ((ushort4*)xbf)[i] = o;
}

// ---------------- prep: weights ----------------
// WxT[n][k] = bf16(W_lstm[k][n]) for k<256 (xproj B-frags contiguous)
// Whp2[p][t] = uint2{packA, packB} for scan thread t (gate-local pairing):
//   t=2j:   colA=j (i), colB=256+j (g) ; t=2j+1: colA=512+j (f), colB=768+j (o)
__global__ void k_prep_w(const float* __restrict__ W, unsigned short* __restrict__ WxT,
                         uint2* __restrict__ Whp2) {
  int i = blockIdx.x * blockDim.x + threadIdx.x;
  if (i < 256 * 1024) {
    int n = i >> 8, k = i & 255;
    WxT[i] = f32_to_bf16(W[k * 1024 + n]);
  } else {
    int v = i - 256 * 1024;        // [0, 65536)
    int p = v >> 9, t = v & 511;
    int j = t >> 1;
    int colA = (t & 1) ? 512 + j : j;
    int colB = (t & 1) ? 768 + j : 256 + j;
    unsigned int aLo = (unsigned int)__builtin_bit_cast(unsigned short, (_Float16)W[(256 + 2 * p) * 1024 + colA]);
    unsigned int aHi = (unsigned int)__builtin_bit_cast(unsigned short, (_Float16)W[(257 + 2 * p) * 1024 + colA]);
    unsigned int bLo = (unsigned int)__builtin_bit_cast(unsigned short, (_Float16)W[(256 + 2 * p) * 1024 + colB]);
    unsigned int bHi = (unsigned int)__builtin_bit_cast(unsigned short, (_Float16)W[(257 + 2 * p) * 1024 + colB]);
    Whp2[v] = uint2{aLo | (aHi << 16), bLo | (bHi << 16)};
  }
}

// ---------------- prep: tail quads (pairs 112..127) for VMEM streaming ----------------
__global__ void k_prep_q(const uint2* __restrict__ Whp2, uint4* __restrict__ Whq4) {
  int v = blockIdx.x * blockDim.x + threadIdx.x;
  if (v >= GQUADS * 512) return;
  int i = v >> 9, t = v & 511;
  int p = RPAIRS + 2 * i;
  uint2 u = Whp2[(size_t)p * 512 + t];
  uint2 w = Whp2[(size_t)(p + 1) * 512 + t];
  Whq4[v] = uint4{u.x, u.y, w.x, w.y};
}

// ---------------- xproj: gates_x = x @ Wx + b (+1 on f-gate) ----------------
// M=131072, N=1024, K=256. Output layout: G[m][j][gate], gate order (i,g,f,o).
__global__ __launch_bounds__(256) void k_xproj(const unsigned short* __restrict__ A,
                                               const unsigned short* __restrict__ BT,
                                               const float* __restrict__ bias,
                                               __half* __restrict__ G) {
  int bm = blockIdx.x * 64;
  int bn = blockIdx.y * 64;
  int lane = threadIdx.x & 63, wave = threadIdx.x >> 6;
  int wm = (wave & 1) * 32, wn = (wave >> 1) * 32;
  int q = lane >> 4, l16 = lane & 15;

  f32x4 acc[2][2] = {};
  const unsigned short* Ab = A + (size_t)(bm + wm + l16) * 256 + q * 8;
  const unsigned short* Bb = BT + (size_t)(bn + wn + l16) * 256 + q * 8;

#pragma unroll
  for (int kk = 0; kk < 8; ++kk) {
    short8 a0 = *(const short8*)(Ab + kk * 32);
    short8 a1 = *(const short8*)(Ab + 16 * 256 + kk * 32);
    short8 b0 = *(const short8*)(Bb + kk * 32);
    short8 b1 = *(const short8*)(Bb + 16 * 256 + kk * 32);
    acc[0][0] = __builtin_amdgcn_mfma_f32_16x16x32_bf16(a0, b0, acc[0][0], 0, 0, 0);
    acc[0][1] = __builtin_amdgcn_mfma_f32_16x16x32_bf16(a0, b1, acc[0][1], 0, 0, 0);
    acc[1][0] = __builtin_amdgcn_mfma_f32_16x16x32_bf16(a1, b0, acc[1][0], 0, 0, 0);
    acc[1][1] = __builtin_amdgcn_mfma_f32_16x16x32_bf16(a1, b1, acc[1][1], 0, 0, 0);
  }

#pragma unroll
  for (int nt = 0; nt < 2; ++nt) {
    int col = bn + wn + nt * 16 + l16;
    float bv = bias[col] + ((col >= 512 && col < 768) ? 1.0f : 0.0f);
    int gate = col >> 8, jj = col & 255;
#pragma unroll
    for (int mt = 0; mt < 2; ++mt) {
#pragma unroll
      for (int r = 0; r < 4; ++r) {
        int row = bm + wm + mt * 16 + q * 4 + r;
        G[(size_t)row * 1024 + jj * 4 + gate] = __float2half_rn(acc[mt][nt][r] + bv);
      }
    }
  }
}

// ---------------- recurrent scan ----------------
// 32 blocks (1 batch/CU) x 512 threads. Thread t: j=t>>1; even->(i,g), odd->(f,o).
__global__ __launch_bounds__(512, 2) void k_scan(const uint2* __restrict__ Whp2,
                                                 const uint4* __restrict__ Whq4,
                                                 const __half* __restrict__ G,
                                                 __half* __restrict__ hgl,
                                                 float* __restrict__ hfin) {
  __shared__ __align__(16) unsigned int h2u[2][64];   // h pairs 64..127, parity dbuf

  int tid = threadIdx.x;
  int b = blockIdx.x;
  int j = tid >> 1;
  int odd = tid & 1;

  // register-resident weights: pairs 0..111 for the 2 owned columns
  unsigned int wA[RPAIRS], wB[RPAIRS];
#pragma unroll
  for (int p = 0; p < RPAIRS; ++p) {
    uint2 w = Whp2[(size_t)p * 512 + tid];
    wA[p] = w.x; wB[p] = w.y;
  }

  __half* hg = hgl + (size_t)b * 512;            // 2 buffers x 128 halves (pairs 0..63)
  if (tid < 64) h2u[0][tid] = 0u;                // h0 upper = 0
  if (tid < 128) hg[tid] = __float2half_rn(0.f); // h0 lower (buf 0) = 0
  float cst = 0.0f;                              // lives in odd lanes

  const unsigned short* gp = (const unsigned short*)G + (size_t)b * T_STEPS * 1024 + j * 4 + odd * 2;
  unsigned int gx_next = *(const unsigned int*)gp;
  const uint4* wq = Whq4 + tid;
  __syncthreads();   // h0 visible (LDS + L2)

  for (int step = 0; step < T_STEPS; ++step) {
    unsigned int gx_cur = gx_next;
    if (step + 1 < T_STEPS)
      gx_next = *(const unsigned int*)(gp + (size_t)(step + 1) * 1024);

    // ---- issue scalar h loads NOW (pairs 0..63 from parity buffer); consume LAST ----
    const unsigned int* hb = (const unsigned int*)(hg + (step & 1) * 128);
    u32x16 H0, H1, H2, H3;
    asm volatile(
        "s_dcache_inv\n\t"
        "s_load_dwordx16 %0, %4, 0x0\n\t"
        "s_load_dwordx16 %1, %4, 0x40\n\t"
        "s_load_dwordx16 %2, %4, 0x80\n\t"
        "s_load_dwordx16 %3, %4, 0xC0"
        : "=s"(H0), "=s"(H1), "=s"(H2), "=s"(H3)
        : "s"(hb)
        : "memory");
    // fence: keep the s_loads hoisted here; do not let the scheduler sink them
    __builtin_amdgcn_sched_barrier(0);

    half2_t gxh = __builtin_bit_cast(half2_t, gx_cur);
    float accA0 = (float)gxh.x, accB0 = (float)gxh.y;
    float accA1 = 0.0f, accB1 = 0.0f;

    const uint4* h2q = (const uint4*)h2u[step & 1];

    // ---- chunks 16..27: resident weights (pairs 64..111), h from LDS uniform ----
#pragma unroll
    for (int ch = 0; ch < 12; ++ch) {
      uint4 hh = h2q[ch];
      accA0 = fdot2f(wA[64 + ch * 4 + 0], hh.x, accA0); accB0 = fdot2f(wB[64 + ch * 4 + 0], hh.x, accB0);
      accA1 = fdot2f(wA[64 + ch * 4 + 1], hh.y, accA1); accB1 = fdot2f(wB[64 + ch * 4 + 1], hh.y, accB1);
      accA0 = fdot2f(wA[64 + ch * 4 + 2], hh.z, accA0); accB0 = fdot2f(wB[64 + ch * 4 + 2], hh.z, accB0);
      accA1 = fdot2f(wA[64 + ch * 4 + 3], hh.w, accA1); accB1 = fdot2f(wB[64 + ch * 4 + 3], hh.w, accB1);
    }
    // ---- chunks 28..31: streamed tail weights (VMEM quads), h from LDS uniform ----
#pragma unroll
    for (int t = 0; t < 4; ++t) {
      uint4 hh = h2q[12 + t];
      uint4 q0 = wq[(2 * t) * 512];
      uint4 q1 = wq[(2 * t + 1) * 512];
      accA0 = fdot2f(q0.x, hh.x, accA0); accB0 = fdot2f(q0.y, hh.x, accB0);
      accA1 = fdot2f(q0.z, hh.y, accA1); accB1 = fdot2f(q0.w, hh.y, accB1);
      accA0 = fdot2f(q1.x, hh.z, accA0); accB0 = fdot2f(q1.y, hh.z, accB0);
      accA1 = fdot2f(q1.z, hh.w, accA1); accB1 = fdot2f(q1.w, hh.w, accB1);
    }

    // ---- SMEM long since landed: chunks 0..15 with h from SGPRs ----
    asm volatile("s_waitcnt lgkmcnt(0)" ::: "memory");
    __builtin_amdgcn_sched_barrier(0);
#define SCHUNK(HV, BASE)                                                     \
    _Pragma("unroll")                                                        \
    for (int i = 0; i < 16; i += 2) {                                        \
      accA0 = fdot2f(wA[(BASE) + i], HV[i], accA0);                          \
      accB0 = fdot2f(wB[(BASE) + i], HV[i], accB0);                          \
      accA1 = fdot2f(wA[(BASE) + i + 1], HV[i + 1], accA1);                  \
      accB1 = fdot2f(wB[(BASE) + i + 1], HV[i + 1], accB1);                  \
    }
    SCHUNK(H0, 0)
    SCHUNK(H1, 16)
    SCHUNK(H2, 32)
    SCHUNK(H3, 48)
#undef SCHUNK

    // ---- epilogue: A = i|f, B = g|o ; cross via shfl_xor(1) ----
    float Av = accA0 + accA1;
    float Bv = accB0 + accB1;
    float sA = 1.0f / (1.0f + __expf(-Av));            // si | sf
    float eB = __expf(2.0f * Bv);
    float tB = 1.0f - 2.0f / (eB + 1.0f);              // tanh(g) | (unused)
    float a = sA * tB;
    float a_x = __shfl_xor(a, 1, 64);
    if (odd) {
      float so = 1.0f / (1.0f + __expf(-Bv));
      cst = sA * cst + a_x;
      float ec = __expf(2.0f * cst);
      float tc = 1.0f - 2.0f / (ec + 1.0f);
      float h = so * tc;
      __half h16 = __float2half_rn(h);
      if (j < 128) hg[((step + 1) & 1) * 128 + j] = h16;                    // lower -> global
      else ((__half*)h2u[(step + 1) & 1])[j - 128] = h16;                   // upper -> LDS
      if (step == T_STEPS - 1) hfin[b * 256 + j] = (float)h;
    }

    __syncthreads();   // drains vmcnt (h->L2 for s_load) + lgkmcnt (LDS h)
  }
}

// ---------------- head: out = (h@Wfc+bfc)@Wout+bout ----------------
__global__ void k_head(const float* __restrict__ hfin, const float* __restrict__ Wfc,
                       const float* __restrict__ bfc, const float* __restrict__ Wout,
                       const float* __restrict__ bout, float* __restrict__ out) {
  __shared__ float hs[256];
  __shared__ float fcs[256];
  int b = blockIdx.x, j = threadIdx.x;
  hs[j] = hfin[b * 256 + j];
  __syncthreads();
  float acc = bfc[j];
#pragma unroll 8
  for (int k = 0; k < 256; ++k) acc += hs[k] * Wfc[k * 256 + j];
  fcs[j] = acc;
  __syncthreads();
  if (j < 24) {
    float a2 = bout[j];
#pragma unroll 8
    for (int k = 0; k < 256; ++k) a2 += fcs[k] * Wout[k * 24 + j];
    out[b * 24 + j] = a2;
  }
}

extern "C" void kernel_launch(void* const* d_in, const int* in_sizes, int n_in,
                              void* d_out, int out_size, void* d_ws, size_t ws_size,
                              hipStream_t stream) {
  const float* x    = (const float*)d_in[0];
  const float* Wl   = (const float*)d_in[1];
  const float* bl   = (const float*)d_in[2];
  const float* Wfc  = (const float*)d_in[3];
  const float* bfc  = (const float*)d_in[4];
  const float* Wout = (const float*)d_in[5];
  const float* bout = (const float*)d_in[6];
  float* out = (float*)d_out;

  char* ws = (char*)d_ws;
  // ws layout (bytes), total ~321 MB
  unsigned short* xbf = (unsigned short*)ws;                    //  67108864  x as bf16
  unsigned short* WxT = (unsigned short*)(ws + 67108864);       //    524288  Wx^T bf16 [1024][256]
  uint2*          Whp2= (uint2*)(ws + 67633152);                //    524288  Wh pairs [128][512]
  __half*         G   = (__half*)(ws + 68157440);               // 268435456  gates_x f16 [m][j][gate]
  float*          hfin= (float*)(ws + 336592896);               //     32768  final h f32
  uint4*          Whq4= (uint4*)(ws + 336625664);               //     65536  tail quads [8][512]
  __half*         hgl = (__half*)(ws + 336691200);              //     32768  h lower dbuf [32][2][128]

  k_prep_x<<<32768, 256, 0, stream>>>((const float4*)x, xbf, 8388608);
  k_prep_w<<<1280, 256, 0, stream>>>(Wl, WxT, Whp2);
  k_prep_q<<<16, 256, 0, stream>>>(Whp2, Whq4);
  dim3 gx(2048, 16, 1);
  k_xproj<<<gx, 256, 0, stream>>>(xbf, WxT, bl, G);
  k_scan<<<32, 512, 0, stream>>>(Whp2, Whq4, G, hgl, hfin);
  k_head<<<32, 256, 0, stream>>>(hfin, Wfc, bfc, Wout, bout, out);
}

// Round 11
// 4716.637 us; speedup vs baseline: 2.4401x; 2.4401x over previous
//
#include <hip/hip_runtime.h>
#include <hip/hip_fp16.h>

// LSTM: B=32, T=4096, D=256, H=256, gates=1024 (i,g,f,o), HORIZON=24
// r11: recurrent matvec in INT8 (v_dot4_i32_i8). Rationale (10-round synthesis):
//   the f16 structure is pinned at ~3700cyc/step by (a) the LDS h-broadcast
//   instruction floor (8 waves x 32 uniform b128 = 256 reads/CU/step) and
//   (b) ~2400cyc VALU (256 fdot2/thread). i8 halves BOTH: h = 256B/wave ->
//   16 reads; 128 dot4/thread; and W_h collapses to 128 VGPRs (fully arch-
//   resident, no AGPR tax, no weight tail anywhere).
//   h in (-1,1) strictly -> fixed scale 127; W_h per-column scale; dequant
//   folded into one fma with f16 gates_x. Skeleton = r8 (gate-local pairing,
//   shfl_xor epilogue, ONE raw barrier/step, parity-dbuf h).

#define T_STEPS 4096
#define BATCH 32

typedef short short8 __attribute__((ext_vector_type(8)));
typedef float f32x4 __attribute__((ext_vector_type(4)));
typedef _Float16 half2_t __attribute__((ext_vector_type(2)));

__device__ inline unsigned short f32_to_bf16(float f) {
  unsigned int u = __builtin_bit_cast(unsigned int, f);
  u = u + 0x7fffu + ((u >> 16) & 1u);   // RNE
  return (unsigned short)(u >> 16);
}

__device__ inline int dot4i8(unsigned int a, unsigned int b, int acc) {
#if __has_builtin(__builtin_amdgcn_sdot4)
  return __builtin_amdgcn_sdot4((int)a, (int)b, acc, false);
#else
  int r = acc;
#pragma unroll
  for (int k = 0; k < 4; ++k) {
    int av = (int)(signed char)((a >> (8 * k)) & 0xff);
    int bv = (int)(signed char)((b >> (8 * k)) & 0xff);
    r += av * bv;
  }
  return r;
#endif
}

// ---------------- prep: x f32 -> bf16 ----------------
__global__ void k_prep_x(const float4* __restrict__ x, unsigned short* __restrict__ xbf, int n4) {
  int i = blockIdx.x * blockDim.x + threadIdx.x;
  if (i >= n4) return;
  float4 v = x[i];
  ushort4 o;
  o.x = f32_to_bf16(v.x); o.y = f32_to_bf16(v.y);
  o.z = f32_to_bf16(v.z); o.w = f32_to_bf16(v.w);
  ((ushort4*)xbf)[i] = o;
}

// ---------------- prep: Wx^T bf16 for xproj ----------------
__global__ void k_prep_wx(const float* __restrict__ W, unsigned short* __restrict__ WxT) {
  int i = blockIdx.x * blockDim.x + threadIdx.x;
  if (i >= 256 * 1024) return;
  int n = i >> 8, k = i & 255;
  WxT[i] = f32_to_bf16(W[k * 1024 + n]);
}

// ---------------- prep: W_h int8 quantization ----------------
// One thread per gate-column c. Per-column scale m = max|W_h[:,c]|.
// Packing: Wq8[p4*1024 + t*2 + slot] = 4 consecutive k-rows (k=4p4..4p4+3, byte b = k offset b).
// Pairing map (r8): c<256 (i): t=2c,slot0 ; c<512 (g): t=2(c-256),slot1 ;
//                   c<768 (f): t=2(c-512)+1,slot0 ; else (o): t=2(c-768)+1,slot1.
// qs[t*2+slot] = m / (127*127)  (dequant: gate_h = dot_i32 * qs).
__global__ void k_prep_w8(const float* __restrict__ W, unsigned int* __restrict__ Wq8,
                          float* __restrict__ qs) {
  int c = blockIdx.x * blockDim.x + threadIdx.x;
  if (c >= 1024) return;
  float m = 0.0f;
  for (int k = 0; k < 256; ++k) m = fmaxf(m, fabsf(W[(256 + k) * 1024 + c]));
  if (m < 1e-20f) m = 1e-20f;
  float inv = 127.0f / m;
  int t, slot;
  if (c < 256)      { t = 2 * c;           slot = 0; }
  else if (c < 512) { t = 2 * (c - 256);   slot = 1; }
  else if (c < 768) { t = 2 * (c - 512) + 1; slot = 0; }
  else              { t = 2 * (c - 768) + 1; slot = 1; }
  for (int p4 = 0; p4 < 64; ++p4) {
    unsigned int d = 0;
    for (int b2 = 0; b2 < 4; ++b2) {
      float w = W[(256 + 4 * p4 + b2) * 1024 + c];
      int wi = (int)rintf(w * inv);
      wi = wi > 127 ? 127 : (wi < -127 ? -127 : wi);
      d |= ((unsigned int)(wi & 0xff)) << (8 * b2);
    }
    Wq8[p4 * 1024 + t * 2 + slot] = d;
  }
  qs[t * 2 + slot] = m / (127.0f * 127.0f);
}

// ---------------- xproj: gates_x = x @ Wx + b (+1 on f-gate) ----------------
// M=131072, N=1024, K=256. Output layout: G[m][j][gate], gate order (i,g,f,o).
__global__ __launch_bounds__(256) void k_xproj(const unsigned short* __restrict__ A,
                                               const unsigned short* __restrict__ BT,
                                               const float* __restrict__ bias,
                                               __half* __restrict__ G) {
  int bm = blockIdx.x * 64;
  int bn = blockIdx.y * 64;
  int lane = threadIdx.x & 63, wave = threadIdx.x >> 6;
  int wm = (wave & 1) * 32, wn = (wave >> 1) * 32;
  int q = lane >> 4, l16 = lane & 15;

  f32x4 acc[2][2] = {};
  const unsigned short* Ab = A + (size_t)(bm + wm + l16) * 256 + q * 8;
  const unsigned short* Bb = BT + (size_t)(bn + wn + l16) * 256 + q * 8;

#pragma unroll
  for (int kk = 0; kk < 8; ++kk) {
    short8 a0 = *(const short8*)(Ab + kk * 32);
    short8 a1 = *(const short8*)(Ab + 16 * 256 + kk * 32);
    short8 b0 = *(const short8*)(Bb + kk * 32);
    short8 b1 = *(const short8*)(Bb + 16 * 256 + kk * 32);
    acc[0][0] = __builtin_amdgcn_mfma_f32_16x16x32_bf16(a0, b0, acc[0][0], 0, 0, 0);
    acc[0][1] = __builtin_amdgcn_mfma_f32_16x16x32_bf16(a0, b1, acc[0][1], 0, 0, 0);
    acc[1][0] = __builtin_amdgcn_mfma_f32_16x16x32_bf16(a1, b0, acc[1][0], 0, 0, 0);
    acc[1][1] = __builtin_amdgcn_mfma_f32_16x16x32_bf16(a1, b1, acc[1][1], 0, 0, 0);
  }

#pragma unroll
  for (int nt = 0; nt < 2; ++nt) {
    int col = bn + wn + nt * 16 + l16;
    float bv = bias[col] + ((col >= 512 && col < 768) ? 1.0f : 0.0f);
    int gate = col >> 8, jj = col & 255;
#pragma unroll
    for (int mt = 0; mt < 2; ++mt) {
#pragma unroll
      for (int r = 0; r < 4; ++r) {
        int row = bm + wm + mt * 16 + q * 4 + r;
        G[(size_t)row * 1024 + jj * 4 + gate] = __float2half_rn(acc[mt][nt][r] + bv);
      }
    }
  }
}

// ---------------- recurrent scan (int8 dot4) ----------------
// 32 blocks (1 batch/CU) x 512 threads. Thread t: j=t>>1; even->(i,g), odd->(f,o).
// W_h: 128 dwords/thread fully register-resident. h: i8[256] in LDS (512B total,
// parity dbuf), read as 16 uniform b128/wave.
__global__ __launch_bounds__(512, 2) void k_scan(const uint2* __restrict__ Wq8,
                                                 const float2* __restrict__ qs,
                                                 const __half* __restrict__ G,
                                                 float* __restrict__ hfin) {
  __shared__ __align__(16) unsigned int h8[2][64];   // h as i8, parity dbuf

  int tid = threadIdx.x;
  int b = blockIdx.x;
  int j = tid >> 1;
  int odd = tid & 1;

  // resident i8 weights: 64 dwords per column x 2 columns
  unsigned int wA[64], wB[64];
#pragma unroll
  for (int p4 = 0; p4 < 64; ++p4) {
    uint2 w = Wq8[p4 * 512 + tid];
    wA[p4] = w.x; wB[p4] = w.y;
  }
  float2 sc = qs[tid];   // dequant scales {A, B}

  if (tid < 64) { h8[0][tid] = 0u; }
  float cst = 0.0f;      // lives in odd lanes

  const unsigned short* gp = (const unsigned short*)G + (size_t)b * T_STEPS * 1024 + j * 4 + odd * 2;
  unsigned int gx_next = *(const unsigned int*)gp;
  __syncthreads();

  for (int step = 0; step < T_STEPS; ++step) {
    unsigned int gx_cur = gx_next;
    if (step + 1 < T_STEPS)
      gx_next = *(const unsigned int*)(gp + (size_t)(step + 1) * 1024);   // stays in flight

    const uint4* hq = (const uint4*)h8[step & 1];

    int accA0 = 0, accB0 = 0, accA1 = 0, accB1 = 0;   // 2 chains per column
#pragma unroll
    for (int ch = 0; ch < 16; ++ch) {
      uint4 hh = hq[ch];
      accA0 = dot4i8(wA[ch * 4 + 0], hh.x, accA0); accB0 = dot4i8(wB[ch * 4 + 0], hh.x, accB0);
      accA1 = dot4i8(wA[ch * 4 + 1], hh.y, accA1); accB1 = dot4i8(wB[ch * 4 + 1], hh.y, accB1);
      accA0 = dot4i8(wA[ch * 4 + 2], hh.z, accA0); accB0 = dot4i8(wB[ch * 4 + 2], hh.z, accB0);
      accA1 = dot4i8(wA[ch * 4 + 3], hh.w, accA1); accB1 = dot4i8(wB[ch * 4 + 3], hh.w, accB1);
    }

    // dequant + add gates_x
    half2_t gxh = __builtin_bit_cast(half2_t, gx_cur);
    float Av = (float)(accA0 + accA1) * sc.x + (float)gxh.x;   // even: i ; odd: f (+1 folded)
    float Bv = (float)(accB0 + accB1) * sc.y + (float)gxh.y;   // even: g ; odd: o

    // epilogue (r8): cross (i,g)->(f,o) lane via shfl_xor(1)
    float sA = 1.0f / (1.0f + __expf(-Av));            // si | sf
    float eB = __expf(2.0f * Bv);
    float tB = 1.0f - 2.0f / (eB + 1.0f);              // tanh(g) | (unused)
    float a = sA * tB;
    float a_x = __shfl_xor(a, 1, 64);
    if (odd) {
      float so = 1.0f / (1.0f + __expf(-Bv));
      cst = sA * cst + a_x;                            // c = sf*c + si*tanh(g)
      float ec = __expf(2.0f * cst);
      float tc = 1.0f - 2.0f / (ec + 1.0f);
      float h = so * tc;                               // |h| < 1 strictly
      int hi = (int)rintf(h * 127.0f);
      ((char*)h8[(step + 1) & 1])[j] = (char)hi;       // ds_write_b8
      if (step == T_STEPS - 1) hfin[b * 256 + j] = h;
    }

    // ONE raw barrier: drain LDS (h8 writes); G-prefetch stays in flight
    asm volatile("s_waitcnt lgkmcnt(0)\n\ts_barrier" ::: "memory");
  }
}

// ---------------- head: out = (h@Wfc+bfc)@Wout+bout ----------------
__global__ void k_head(const float* __restrict__ hfin, const float* __restrict__ Wfc,
                       const float* __restrict__ bfc, const float* __restrict__ Wout,
                       const float* __restrict__ bout, float* __restrict__ out) {
  __shared__ float hs[256];
  __shared__ float fcs[256];
  int b = blockIdx.x, j = threadIdx.x;
  hs[j] = hfin[b * 256 + j];
  __syncthreads();
  float acc = bfc[j];
#pragma unroll 8
  for (int k = 0; k < 256; ++k) acc += hs[k] * Wfc[k * 256 + j];
  fcs[j] = acc;
  __syncthreads();
  if (j < 24) {
    float a2 = bout[j];
#pragma unroll 8
    for (int k = 0; k < 256; ++k) a2 += fcs[k] * Wout[k * 24 + j];
    out[b * 24 + j] = a2;
  }
}

extern "C" void kernel_launch(void* const* d_in, const int* in_sizes, int n_in,
                              void* d_out, int out_size, void* d_ws, size_t ws_size,
                              hipStream_t stream) {
  const float* x    = (const float*)d_in[0];
  const float* Wl   = (const float*)d_in[1];
  const float* bl   = (const float*)d_in[2];
  const float* Wfc  = (const float*)d_in[3];
  const float* bfc  = (const float*)d_in[4];
  const float* Wout = (const float*)d_in[5];
  const float* bout = (const float*)d_in[6];
  float* out = (float*)d_out;

  char* ws = (char*)d_ws;
  // ws layout (bytes), total ~321 MB
  unsigned short* xbf = (unsigned short*)ws;                    //  67108864  x as bf16
  unsigned short* WxT = (unsigned short*)(ws + 67108864);       //    524288  Wx^T bf16 [1024][256]
  unsigned int*   Wq8 = (unsigned int*)(ws + 67633152);         //    262144  Wh i8 [64][512][2]
  float*          qsb = (float*)(ws + 67895296);                //      4096  dequant scales [512][2]
  __half*         G   = (__half*)(ws + 68157440);               // 268435456  gates_x f16 [m][j][gate]
  float*          hfin= (float*)(ws + 336592896);               //     32768  final h f32

  k_prep_x<<<32768, 256, 0, stream>>>((const float4*)x, xbf, 8388608);
  k_prep_wx<<<1024, 256, 0, stream>>>(Wl, WxT);
  k_prep_w8<<<4, 256, 0, stream>>>(Wl, Wq8, qsb);
  dim3 gx(2048, 16, 1);
  k_xproj<<<gx, 256, 0, stream>>>(xbf, WxT, bl, G);
  k_scan<<<32, 512, 0, stream>>>((const uint2*)Wq8, (const float2*)qsb, G, hfin);
  k_head<<<32, 256, 0, stream>>>(hfin, Wfc, bfc, Wout, bout, out);
}